// Round 1
// baseline (7751.471 us; speedup 1.0000x reference)
//
#include <hip/hip_runtime.h>
#include <cstdint>
#include <cstddef>

static inline int cdiv(int a, int b) { return (a + b - 1) / b; }

// ---------------- CSR build (counting sort by dst) ----------------

__global__ void count_deg_kernel(const int* __restrict__ dst, int* __restrict__ deg, int nE) {
    int i = blockIdx.x * blockDim.x + threadIdx.x;
    if (i < nE) atomicAdd(&deg[dst[i]], 1);
}

// single-block sequential-chunk exclusive scan; also writes cursor copy
__global__ void scan_kernel(const int* __restrict__ deg, int* __restrict__ rowptr,
                            int* __restrict__ cursor, int n) {
    __shared__ int sdata[256];
    __shared__ int carry_s;
    int tid = threadIdx.x;
    if (tid == 0) carry_s = 0;
    __syncthreads();
    for (int base = 0; base < n; base += 1024) {
        int vals[4];
        int local = 0;
#pragma unroll
        for (int i = 0; i < 4; ++i) {
            int idx = base + tid * 4 + i;
            vals[i] = (idx < n) ? deg[idx] : 0;
            local += vals[i];
        }
        sdata[tid] = local;
        __syncthreads();
        // inclusive scan over 256 thread sums
        for (int off = 1; off < 256; off <<= 1) {
            int t = (tid >= off) ? sdata[tid - off] : 0;
            __syncthreads();
            sdata[tid] += t;
            __syncthreads();
        }
        int excl = sdata[tid] - local;
        int c0 = carry_s;
        int run = c0 + excl;
#pragma unroll
        for (int i = 0; i < 4; ++i) {
            int idx = base + tid * 4 + i;
            if (idx < n) { rowptr[idx] = run; cursor[idx] = run; }
            run += vals[i];
        }
        __syncthreads();
        if (tid == 255) carry_s = c0 + sdata[255];
        __syncthreads();
    }
    if (tid == 0) rowptr[n] = carry_s;
}

__global__ void scatter_kernel(const int* __restrict__ src, const int* __restrict__ dst,
                               const float* __restrict__ w, int* __restrict__ cursor,
                               int* __restrict__ src_sorted, float* __restrict__ w_sorted,
                               int nE) {
    int i = blockIdx.x * blockDim.x + threadIdx.x;
    if (i < nE) {
        int d = dst[i];
        int pos = atomicAdd(&cursor[d], 1);
        src_sorted[pos] = src[i];
        w_sorted[pos]  = w[i];
    }
}

// ---------------- fp32 tiled GEMM: C[M,N] = A[M,K] @ B[K,N] ----------------
// BM=BN=64, BK=32, 256 threads, 4x4 per thread

__global__ __launch_bounds__(256) void gemm_kernel(const float* __restrict__ A,
                                                   const float* __restrict__ B,
                                                   float* __restrict__ C,
                                                   int M, int K, int N) {
    __shared__ float As[32][65];  // [k][m], padded
    __shared__ float Bs[32][65];  // [k][n], padded
    int tid = threadIdx.x;
    int tx = tid & 15, ty = tid >> 4;
    int m0 = blockIdx.x * 64, n0 = blockIdx.y * 64;
    float acc[4][4] = {};
    for (int k0 = 0; k0 < K; k0 += 32) {
        // load A tile 64x32 (K assumed multiple of 32)
#pragma unroll
        for (int it = 0; it < 8; ++it) {
            int idx = tid + it * 256;
            int r = idx >> 5, c = idx & 31;
            int gm = m0 + r;
            As[c][r] = (gm < M) ? A[(size_t)gm * K + k0 + c] : 0.f;
        }
        // load B tile 32x64
#pragma unroll
        for (int it = 0; it < 8; ++it) {
            int idx = tid + it * 256;
            int nn = idx & 63, c = idx >> 6;
            int gn = n0 + nn;
            Bs[c][nn] = (gn < N) ? B[(size_t)(k0 + c) * N + gn] : 0.f;
        }
        __syncthreads();
#pragma unroll
        for (int k = 0; k < 32; ++k) {
            float a[4], b[4];
#pragma unroll
            for (int i = 0; i < 4; ++i) a[i] = As[k][ty * 4 + i];
#pragma unroll
            for (int j = 0; j < 4; ++j) b[j] = Bs[k][tx * 4 + j];
#pragma unroll
            for (int i = 0; i < 4; ++i)
#pragma unroll
                for (int j = 0; j < 4; ++j)
                    acc[i][j] += a[i] * b[j];
        }
        __syncthreads();
    }
#pragma unroll
    for (int i = 0; i < 4; ++i) {
        int gm = m0 + ty * 4 + i;
        if (gm >= M) continue;
#pragma unroll
        for (int j = 0; j < 4; ++j) {
            int gn = n0 + tx * 4 + j;
            if (gn < N) C[(size_t)gm * N + gn] = acc[i][j];
        }
    }
}

// ---------------- CSR aggregation: out[i] = relu(sum_e w*support[src] + b) ----------------
// one wave (64 lanes) per node

template <int FO, bool RELU>
__global__ __launch_bounds__(256) void agg_kernel(const float* __restrict__ support,
                                                  const int* __restrict__ srcs,
                                                  const float* __restrict__ ws,
                                                  const int* __restrict__ rowptr,
                                                  const float* __restrict__ bias,
                                                  float* __restrict__ out, int n_nodes) {
    int node = (int)((blockIdx.x * blockDim.x + threadIdx.x) >> 6);
    int lane = threadIdx.x & 63;
    if (node >= n_nodes) return;
    int beg = rowptr[node], end = rowptr[node + 1];
    if constexpr (FO == 256) {
        float4 acc = {0.f, 0.f, 0.f, 0.f};
        for (int e = beg; e < end; ++e) {
            int s = srcs[e];
            float w = ws[e];
            float4 v = *reinterpret_cast<const float4*>(support + (size_t)s * 256 + lane * 4);
            acc.x += w * v.x; acc.y += w * v.y; acc.z += w * v.z; acc.w += w * v.w;
        }
        float4 b = *reinterpret_cast<const float4*>(bias + lane * 4);
        acc.x += b.x; acc.y += b.y; acc.z += b.z; acc.w += b.w;
        if (RELU) {
            acc.x = fmaxf(acc.x, 0.f); acc.y = fmaxf(acc.y, 0.f);
            acc.z = fmaxf(acc.z, 0.f); acc.w = fmaxf(acc.w, 0.f);
        }
        *reinterpret_cast<float4*>(out + (size_t)node * 256 + lane * 4) = acc;
    } else if constexpr (FO == 128) {
        float2 acc = {0.f, 0.f};
        for (int e = beg; e < end; ++e) {
            int s = srcs[e];
            float w = ws[e];
            float2 v = *reinterpret_cast<const float2*>(support + (size_t)s * 128 + lane * 2);
            acc.x += w * v.x; acc.y += w * v.y;
        }
        float2 b = *reinterpret_cast<const float2*>(bias + lane * 2);
        acc.x += b.x; acc.y += b.y;
        if (RELU) { acc.x = fmaxf(acc.x, 0.f); acc.y = fmaxf(acc.y, 0.f); }
        *reinterpret_cast<float2*>(out + (size_t)node * 128 + lane * 2) = acc;
    } else {  // FO == 64
        float acc = 0.f;
        for (int e = beg; e < end; ++e) {
            int s = srcs[e];
            float w = ws[e];
            acc += w * support[(size_t)s * 64 + lane];
        }
        acc += bias[lane];
        if (RELU) acc = fmaxf(acc, 0.f);
        out[(size_t)node * 64 + lane] = acc;
    }
}

// ---------------- final layer: aggregation + bias + log_softmax over 40 ----------------

__global__ __launch_bounds__(256) void agg_lsm_kernel(const float* __restrict__ support,
                                                      const int* __restrict__ srcs,
                                                      const float* __restrict__ ws,
                                                      const int* __restrict__ rowptr,
                                                      const float* __restrict__ bias,
                                                      float* __restrict__ out, int n_nodes) {
    int node = (int)((blockIdx.x * blockDim.x + threadIdx.x) >> 6);
    int lane = threadIdx.x & 63;
    if (node >= n_nodes) return;
    int beg = rowptr[node], end = rowptr[node + 1];
    float acc = 0.f;
    for (int e = beg; e < end; ++e) {
        int s = srcs[e];
        float w = ws[e];
        if (lane < 40) acc += w * support[(size_t)s * 40 + lane];
    }
    float v = (lane < 40) ? (acc + bias[lane]) : -1e30f;
    float m = v;
    for (int off = 32; off; off >>= 1) m = fmaxf(m, __shfl_xor(m, off));
    float ex = (lane < 40) ? expf(v - m) : 0.f;
    float s = ex;
    for (int off = 32; off; off >>= 1) s += __shfl_xor(s, off);
    float ls = logf(s);
    if (lane < 40) out[(size_t)node * 40 + lane] = v - m - ls;
}

// ---------------- launch ----------------

extern "C" void kernel_launch(void* const* d_in, const int* in_sizes, int n_in,
                              void* d_out, int out_size, void* d_ws, size_t ws_size,
                              hipStream_t stream) {
    const float* x    = (const float*)d_in[0];
    const int*   esrc = (const int*)d_in[1];
    const int*   edst = (const int*)d_in[2];
    const float* ew   = (const float*)d_in[3];
    const float* W[9];
    const float* b[9];
    for (int i = 0; i < 9; ++i) {
        W[i] = (const float*)d_in[4 + 2 * i];
        b[i] = (const float*)d_in[5 + 2 * i];
    }
    const int nN = in_sizes[0] / 512;  // 100000
    const int nE = in_sizes[1];        // 3200000

    char* ws = (char*)d_ws;
    float* bufA = (float*)ws;                              // nN*256 f32 (support)
    float* bufB = (float*)(ws + (size_t)nN * 256 * 4);     // nN*256 f32 (h)
    char* p = ws + (size_t)nN * 256 * 4 * 2;
    int* deg    = (int*)p; p += ((size_t)nN + 64) * 4;
    int* rowptr = (int*)p; p += ((size_t)nN + 64) * 4;
    int* cursor = (int*)p; p += ((size_t)nN + 64) * 4;
    int* src_sorted = (int*)p; p += (size_t)nE * 4;
    float* w_sorted = (float*)p; p += (size_t)nE * 4;

    // build CSR (per call; deg must be re-zeroed every launch)
    hipMemsetAsync(deg, 0, (size_t)nN * 4, stream);
    count_deg_kernel<<<cdiv(nE, 256), 256, 0, stream>>>(edst, deg, nE);
    scan_kernel<<<1, 256, 0, stream>>>(deg, rowptr, cursor, nN);
    scatter_kernel<<<cdiv(nE, 256), 256, 0, stream>>>(esrc, edst, ew, cursor,
                                                      src_sorted, w_sorted, nE);

    const int dims[10] = {512, 256, 256, 256, 256, 256, 128, 128, 64, 40};
    const int aggBlocks = cdiv(nN, 4);  // 4 waves per 256-thread block, 1 node per wave

    const float* h = x;
    for (int L = 0; L < 9; ++L) {
        int fi = dims[L], fo = dims[L + 1];
        dim3 g(cdiv(nN, 64), cdiv(fo, 64));
        gemm_kernel<<<g, 256, 0, stream>>>(h, W[L], bufA, nN, fi, fo);
        if (L < 8) {
            if (fo == 256)
                agg_kernel<256, true><<<aggBlocks, 256, 0, stream>>>(
                    bufA, src_sorted, w_sorted, rowptr, b[L], bufB, nN);
            else if (fo == 128)
                agg_kernel<128, true><<<aggBlocks, 256, 0, stream>>>(
                    bufA, src_sorted, w_sorted, rowptr, b[L], bufB, nN);
            else  // fo == 64
                agg_kernel<64, true><<<aggBlocks, 256, 0, stream>>>(
                    bufA, src_sorted, w_sorted, rowptr, b[L], bufB, nN);
            h = bufB;
        } else {
            agg_lsm_kernel<<<aggBlocks, 256, 0, stream>>>(
                bufA, src_sorted, w_sorted, rowptr, b[L], (float*)d_out, nN);
        }
    }
}

// Round 2
// 4208.690 us; speedup vs baseline: 1.8418x; 1.8418x over previous
//
#include <hip/hip_runtime.h>
#include <cstdint>
#include <cstddef>

typedef __attribute__((ext_vector_type(8))) short bf16x8;   // 8 bf16 in 4 VGPRs
typedef __attribute__((ext_vector_type(4))) float f32x4;    // MFMA accumulator

static inline int cdiv(int a, int b) { return (a + b - 1) / b; }

__device__ inline unsigned short f2bf(float f) {
    union { float f; unsigned int u; } v; v.f = f;
    unsigned int u = v.u;
    return (unsigned short)((u + 0x7FFFu + ((u >> 16) & 1u)) >> 16);  // RNE
}
__device__ inline float bf2f(unsigned short b) {
    union { unsigned int u; float f; } v; v.u = ((unsigned int)b) << 16;
    return v.f;
}

// ---------------- CSR build (counting sort by dst) ----------------

__global__ void count_deg_kernel(const int* __restrict__ dst, int* __restrict__ deg, int nE) {
    int i = blockIdx.x * blockDim.x + threadIdx.x;
    if (i < nE) atomicAdd(&deg[dst[i]], 1);
}

__global__ void scan_kernel(const int* __restrict__ deg, int* __restrict__ rowptr,
                            int* __restrict__ cursor, int n) {
    __shared__ int sdata[256];
    __shared__ int carry_s;
    int tid = threadIdx.x;
    if (tid == 0) carry_s = 0;
    __syncthreads();
    for (int base = 0; base < n; base += 1024) {
        int vals[4];
        int local = 0;
#pragma unroll
        for (int i = 0; i < 4; ++i) {
            int idx = base + tid * 4 + i;
            vals[i] = (idx < n) ? deg[idx] : 0;
            local += vals[i];
        }
        sdata[tid] = local;
        __syncthreads();
        for (int off = 1; off < 256; off <<= 1) {
            int t = (tid >= off) ? sdata[tid - off] : 0;
            __syncthreads();
            sdata[tid] += t;
            __syncthreads();
        }
        int excl = sdata[tid] - local;
        int c0 = carry_s;
        int run = c0 + excl;
#pragma unroll
        for (int i = 0; i < 4; ++i) {
            int idx = base + tid * 4 + i;
            if (idx < n) { rowptr[idx] = run; cursor[idx] = run; }
            run += vals[i];
        }
        __syncthreads();
        if (tid == 255) carry_s = c0 + sdata[255];
        __syncthreads();
    }
    if (tid == 0) rowptr[n] = carry_s;
}

__global__ void scatter_kernel(const int* __restrict__ src, const int* __restrict__ dst,
                               const float* __restrict__ w, int* __restrict__ cursor,
                               int* __restrict__ src_sorted, float* __restrict__ w_sorted,
                               int nE) {
    int i = blockIdx.x * blockDim.x + threadIdx.x;
    if (i < nE) {
        int d = dst[i];
        int pos = atomicAdd(&cursor[d], 1);
        src_sorted[pos] = src[i];
        w_sorted[pos]  = w[i];
    }
}

// ---------------- weight f32 -> bf16 conversion ----------------

__global__ void cvt_kernel(const float* __restrict__ in, unsigned short* __restrict__ out, int n4) {
    int i = blockIdx.x * blockDim.x + threadIdx.x;
    if (i < n4) {
        float4 v = *reinterpret_cast<const float4*>(in + (size_t)i * 4);
        ushort4 o;
        o.x = f2bf(v.x); o.y = f2bf(v.y); o.z = f2bf(v.z); o.w = f2bf(v.w);
        *reinterpret_cast<ushort4*>(out + (size_t)i * 4) = o;
    }
}

// ---------------- bf16 MFMA GEMM: C[M,N] = A[M,K] @ B[K,N] ----------------
// BM=128, BK=64, 256 threads (4 waves). BN=128: waves 2x2 (64x64 each).
// BN=64: waves 4x1 (32x64 each). LDS padded pitch 80 bf16 (160 B) ->
// conflict-free ds_read_b128 frag loads. A input either f32 (layer 1) or bf16.

template <int BN, bool AF32>
__global__ __launch_bounds__(256) void gemm_bf16(const void* __restrict__ Av,
                                                 const unsigned short* __restrict__ B,
                                                 unsigned short* __restrict__ C,
                                                 int M, int K, int N) {
    constexpr int BM = 128, BK = 64, PITCH = 80;
    __shared__ short As[BM * PITCH];
    __shared__ short Bs[BN * PITCH];
    const int tid = threadIdx.x;
    const int lane = tid & 63, wid = tid >> 6;
    const int m0 = blockIdx.x * BM, n0 = blockIdx.y * BN;

    constexpr int WN = (BN == 128) ? 2 : 1;       // waves along N
    constexpr int WTM = (BN == 128) ? 64 : 32;    // wave tile M
    constexpr int WTN = 64;                       // wave tile N
    constexpr int FM = WTM / 16;
    constexpr int FN = WTN / 16;
    const int wm = (wid / WN) * WTM;
    const int wn = (wid % WN) * WTN;
    const int g = lane >> 4, r16 = lane & 15;

    f32x4 acc[FM][FN];
#pragma unroll
    for (int i = 0; i < FM; ++i)
#pragma unroll
        for (int j = 0; j < FN; ++j)
#pragma unroll
            for (int r = 0; r < 4; ++r) acc[i][j][r] = 0.f;

    for (int k0 = 0; k0 < K; k0 += BK) {
        // ---- stage A tile 128x64 (chunks of 8 bf16, 16B LDS writes) ----
#pragma unroll
        for (int it = 0; it < 4; ++it) {
            int c = it * 256 + tid;           // 1024 chunks
            int r = c >> 3, kc = c & 7;
            int gm = m0 + r;
            bf16x8 val;
            if (gm < M) {
                if constexpr (AF32) {
                    const float* A32 = (const float*)Av;
                    const float* p = A32 + (size_t)gm * K + k0 + kc * 8;
                    float4 v0 = *reinterpret_cast<const float4*>(p);
                    float4 v1 = *reinterpret_cast<const float4*>(p + 4);
                    val[0] = (short)f2bf(v0.x); val[1] = (short)f2bf(v0.y);
                    val[2] = (short)f2bf(v0.z); val[3] = (short)f2bf(v0.w);
                    val[4] = (short)f2bf(v1.x); val[5] = (short)f2bf(v1.y);
                    val[6] = (short)f2bf(v1.z); val[7] = (short)f2bf(v1.w);
                } else {
                    const unsigned short* A16 = (const unsigned short*)Av;
                    val = *reinterpret_cast<const bf16x8*>(A16 + (size_t)gm * K + k0 + kc * 8);
                }
            } else {
#pragma unroll
                for (int j = 0; j < 8; ++j) val[j] = 0;
            }
            *reinterpret_cast<bf16x8*>(&As[r * PITCH + kc * 8]) = val;
        }
        // ---- stage B tile 64xBN transposed -> Bs[n][k] ----
        constexpr int BIT = (64 * BN / 8) / 256;   // 4 for BN=128, 2 for BN=64
#pragma unroll
        for (int it = 0; it < BIT; ++it) {
            int c = it * 256 + tid;
            int k = c & 63, nc = c >> 6;
            int gk = k0 + k;
#pragma unroll
            for (int j = 0; j < 8; ++j) {
                int gn = n0 + nc * 8 + j;
                short v = (gn < N) ? (short)B[(size_t)gk * N + gn] : (short)0;
                Bs[(nc * 8 + j) * PITCH + k] = v;
            }
        }
        __syncthreads();
        // ---- compute: 2 k-substeps of 32 ----
#pragma unroll
        for (int ks = 0; ks < 2; ++ks) {
            bf16x8 af[FM], bfr[FN];
#pragma unroll
            for (int i = 0; i < FM; ++i)
                af[i] = *reinterpret_cast<const bf16x8*>(&As[(wm + i * 16 + r16) * PITCH + ks * 32 + g * 8]);
#pragma unroll
            for (int j = 0; j < FN; ++j)
                bfr[j] = *reinterpret_cast<const bf16x8*>(&Bs[(wn + j * 16 + r16) * PITCH + ks * 32 + g * 8]);
#pragma unroll
            for (int i = 0; i < FM; ++i)
#pragma unroll
                for (int j = 0; j < FN; ++j)
                    acc[i][j] = __builtin_amdgcn_mfma_f32_16x16x32_bf16(af[i], bfr[j], acc[i][j], 0, 0, 0);
        }
        __syncthreads();
    }
    // ---- epilogue: D frag layout col=lane&15, row=(lane>>4)*4+r ----
#pragma unroll
    for (int i = 0; i < FM; ++i) {
        int gmBase = m0 + wm + i * 16 + g * 4;
#pragma unroll
        for (int j = 0; j < FN; ++j) {
            int gn = n0 + wn + j * 16 + r16;
            if (gn < N) {
#pragma unroll
                for (int r = 0; r < 4; ++r) {
                    int gm = gmBase + r;
                    if (gm < M) C[(size_t)gm * N + gn] = f2bf(acc[i][j][r]);
                }
            }
        }
    }
}

// ---------------- CSR aggregation (bf16 support -> bf16 h), fused bias+ReLU ----------------
// one wave per node

template <int FO>
__global__ __launch_bounds__(256) void agg_kernel(const unsigned short* __restrict__ supp,
                                                  const int* __restrict__ srcs,
                                                  const float* __restrict__ ws,
                                                  const int* __restrict__ rowptr,
                                                  const float* __restrict__ bias,
                                                  unsigned short* __restrict__ out, int n_nodes) {
    int node = (int)((blockIdx.x * blockDim.x + threadIdx.x) >> 6);
    int lane = threadIdx.x & 63;
    if (node >= n_nodes) return;
    int beg = rowptr[node], end = rowptr[node + 1];
    if constexpr (FO == 256) {
        float a0 = 0.f, a1 = 0.f, a2 = 0.f, a3 = 0.f;
        for (int e = beg; e < end; ++e) {
            int s = srcs[e];
            float w = ws[e];
            ushort4 v = *reinterpret_cast<const ushort4*>(supp + (size_t)s * 256 + lane * 4);
            a0 += w * bf2f(v.x); a1 += w * bf2f(v.y);
            a2 += w * bf2f(v.z); a3 += w * bf2f(v.w);
        }
        float4 b = *reinterpret_cast<const float4*>(bias + lane * 4);
        a0 = fmaxf(a0 + b.x, 0.f); a1 = fmaxf(a1 + b.y, 0.f);
        a2 = fmaxf(a2 + b.z, 0.f); a3 = fmaxf(a3 + b.w, 0.f);
        ushort4 o = { f2bf(a0), f2bf(a1), f2bf(a2), f2bf(a3) };
        *reinterpret_cast<ushort4*>(out + (size_t)node * 256 + lane * 4) = o;
    } else if constexpr (FO == 128) {
        float a0 = 0.f, a1 = 0.f;
        for (int e = beg; e < end; ++e) {
            int s = srcs[e];
            float w = ws[e];
            ushort2 v = *reinterpret_cast<const ushort2*>(supp + (size_t)s * 128 + lane * 2);
            a0 += w * bf2f(v.x); a1 += w * bf2f(v.y);
        }
        float2 b = *reinterpret_cast<const float2*>(bias + lane * 2);
        a0 = fmaxf(a0 + b.x, 0.f); a1 = fmaxf(a1 + b.y, 0.f);
        ushort2 o = { f2bf(a0), f2bf(a1) };
        *reinterpret_cast<ushort2*>(out + (size_t)node * 128 + lane * 2) = o;
    } else {  // FO == 64
        float a0 = 0.f;
        for (int e = beg; e < end; ++e) {
            int s = srcs[e];
            float w = ws[e];
            a0 += w * bf2f(supp[(size_t)s * 64 + lane]);
        }
        a0 = fmaxf(a0 + bias[lane], 0.f);
        out[(size_t)node * 64 + lane] = f2bf(a0);
    }
}

// ---------------- final layer: aggregation + bias + log_softmax over 40 (f32 out) ----------------

__global__ __launch_bounds__(256) void agg_lsm_kernel(const unsigned short* __restrict__ supp,
                                                      const int* __restrict__ srcs,
                                                      const float* __restrict__ ws,
                                                      const int* __restrict__ rowptr,
                                                      const float* __restrict__ bias,
                                                      float* __restrict__ out, int n_nodes) {
    int node = (int)((blockIdx.x * blockDim.x + threadIdx.x) >> 6);
    int lane = threadIdx.x & 63;
    if (node >= n_nodes) return;
    int beg = rowptr[node], end = rowptr[node + 1];
    float acc = 0.f;
    for (int e = beg; e < end; ++e) {
        int s = srcs[e];
        float w = ws[e];
        if (lane < 40) acc += w * bf2f(supp[(size_t)s * 40 + lane]);
    }
    float v = (lane < 40) ? (acc + bias[lane]) : -1e30f;
    float m = v;
    for (int off = 32; off; off >>= 1) m = fmaxf(m, __shfl_xor(m, off));
    float ex = (lane < 40) ? expf(v - m) : 0.f;
    float s = ex;
    for (int off = 32; off; off >>= 1) s += __shfl_xor(s, off);
    float ls = logf(s);
    if (lane < 40) out[(size_t)node * 40 + lane] = v - m - ls;
}

// ---------------- launch ----------------

extern "C" void kernel_launch(void* const* d_in, const int* in_sizes, int n_in,
                              void* d_out, int out_size, void* d_ws, size_t ws_size,
                              hipStream_t stream) {
    const float* x    = (const float*)d_in[0];
    const int*   esrc = (const int*)d_in[1];
    const int*   edst = (const int*)d_in[2];
    const float* ew   = (const float*)d_in[3];
    const float* W[9];
    const float* b[9];
    for (int i = 0; i < 9; ++i) {
        W[i] = (const float*)d_in[4 + 2 * i];
        b[i] = (const float*)d_in[5 + 2 * i];
    }
    const int nN = in_sizes[0] / 512;  // 100000
    const int nE = in_sizes[1];        // 3200000

    const int dims[10] = {512, 256, 256, 256, 256, 256, 128, 128, 64, 40};

    char* ws = (char*)d_ws;
    unsigned short* supp = (unsigned short*)ws;                        // nN*256 bf16
    unsigned short* h0   = (unsigned short*)(ws + (size_t)nN * 256 * 2);
    unsigned short* h1   = (unsigned short*)(ws + (size_t)nN * 256 * 2 * 2);
    char* p = ws + (size_t)nN * 256 * 2 * 3;
    unsigned short* Wb = (unsigned short*)p; p += (1 << 20);           // 1 MB for all bf16 weights
    int* deg    = (int*)p; p += ((size_t)nN + 64) * 4;
    int* rowptr = (int*)p; p += ((size_t)nN + 64) * 4;
    int* cursor = (int*)p; p += ((size_t)nN + 64) * 4;
    int* src_sorted = (int*)p; p += (size_t)nE * 4;
    float* w_sorted = (float*)p; p += (size_t)nE * 4;

    // ---- convert weights to bf16 ----
    size_t woff[9];
    {
        size_t off = 0;
        for (int i = 0; i < 9; ++i) {
            woff[i] = off;
            int sz = dims[i] * dims[i + 1];
            cvt_kernel<<<cdiv(sz / 4, 256), 256, 0, stream>>>(W[i], Wb + off, sz / 4);
            off += (size_t)sz;
        }
    }

    // ---- build CSR ----
    hipMemsetAsync(deg, 0, (size_t)nN * 4, stream);
    count_deg_kernel<<<cdiv(nE, 256), 256, 0, stream>>>(edst, deg, nE);
    scan_kernel<<<1, 256, 0, stream>>>(deg, rowptr, cursor, nN);
    scatter_kernel<<<cdiv(nE, 256), 256, 0, stream>>>(esrc, edst, ew, cursor,
                                                      src_sorted, w_sorted, nE);

    const int aggBlocks = cdiv(nN, 4);  // 4 waves/block, 1 node/wave
    unsigned short* hbuf[2] = {h0, h1};
    const void* A = (const void*)x;
    int pp = 0;

    for (int L = 0; L < 9; ++L) {
        int fi = dims[L], fo = dims[L + 1];
        int BN = (fo >= 128) ? 128 : 64;
        dim3 g(cdiv(nN, 128), cdiv(fo, BN));
        if (L == 0) {
            gemm_bf16<128, true><<<g, 256, 0, stream>>>(A, Wb + woff[L], supp, nN, fi, fo);
        } else if (BN == 128) {
            gemm_bf16<128, false><<<g, 256, 0, stream>>>(A, Wb + woff[L], supp, nN, fi, fo);
        } else {
            gemm_bf16<64, false><<<g, 256, 0, stream>>>(A, Wb + woff[L], supp, nN, fi, fo);
        }
        if (L < 8) {
            if (fo == 256)
                agg_kernel<256><<<aggBlocks, 256, 0, stream>>>(
                    supp, src_sorted, w_sorted, rowptr, b[L], hbuf[pp], nN);
            else if (fo == 128)
                agg_kernel<128><<<aggBlocks, 256, 0, stream>>>(
                    supp, src_sorted, w_sorted, rowptr, b[L], hbuf[pp], nN);
            else
                agg_kernel<64><<<aggBlocks, 256, 0, stream>>>(
                    supp, src_sorted, w_sorted, rowptr, b[L], hbuf[pp], nN);
            A = (const void*)hbuf[pp];
            pp ^= 1;
        } else {
            agg_lsm_kernel<<<aggBlocks, 256, 0, stream>>>(
                supp, src_sorted, w_sorted, rowptr, b[8], (float*)d_out, nN);
        }
    }
}

// Round 3
// 2500.868 us; speedup vs baseline: 3.0995x; 1.6829x over previous
//
#include <hip/hip_runtime.h>
#include <cstdint>
#include <cstddef>

typedef __attribute__((ext_vector_type(8))) short bf16x8;   // 8 bf16 in 4 VGPRs
typedef __attribute__((ext_vector_type(4))) float f32x4;    // MFMA accumulator

static inline int cdiv(int a, int b) { return (a + b - 1) / b; }

__device__ inline unsigned short f2bf(float f) {
    union { float f; unsigned int u; } v; v.f = f;
    unsigned int u = v.u;
    return (unsigned short)((u + 0x7FFFu + ((u >> 16) & 1u)) >> 16);  // RNE
}
__device__ inline float bf2f(unsigned short b) {
    union { unsigned int u; float f; } v; v.u = ((unsigned int)b) << 16;
    return v.f;
}

// ---------------- CSR build (counting sort by dst) ----------------

__global__ void count_deg_kernel(const int* __restrict__ dst, int* __restrict__ deg, int nE) {
    int i = blockIdx.x * blockDim.x + threadIdx.x;
    if (i < nE) atomicAdd(&deg[dst[i]], 1);
}

__global__ void scan_kernel(const int* __restrict__ deg, int* __restrict__ rowptr,
                            int* __restrict__ cursor, int n) {
    __shared__ int sdata[256];
    __shared__ int carry_s;
    int tid = threadIdx.x;
    if (tid == 0) carry_s = 0;
    __syncthreads();
    for (int base = 0; base < n; base += 1024) {
        int vals[4];
        int local = 0;
#pragma unroll
        for (int i = 0; i < 4; ++i) {
            int idx = base + tid * 4 + i;
            vals[i] = (idx < n) ? deg[idx] : 0;
            local += vals[i];
        }
        sdata[tid] = local;
        __syncthreads();
        for (int off = 1; off < 256; off <<= 1) {
            int t = (tid >= off) ? sdata[tid - off] : 0;
            __syncthreads();
            sdata[tid] += t;
            __syncthreads();
        }
        int excl = sdata[tid] - local;
        int c0 = carry_s;
        int run = c0 + excl;
#pragma unroll
        for (int i = 0; i < 4; ++i) {
            int idx = base + tid * 4 + i;
            if (idx < n) { rowptr[idx] = run; cursor[idx] = run; }
            run += vals[i];
        }
        __syncthreads();
        if (tid == 255) carry_s = c0 + sdata[255];
        __syncthreads();
    }
    if (tid == 0) rowptr[n] = carry_s;
}

__global__ void scatter_kernel(const int* __restrict__ src, const int* __restrict__ dst,
                               const float* __restrict__ w, int* __restrict__ cursor,
                               int2* __restrict__ ep, int nE) {
    int i = blockIdx.x * blockDim.x + threadIdx.x;
    if (i < nE) {
        int d = dst[i];
        int pos = atomicAdd(&cursor[d], 1);
        ep[pos] = make_int2(src[i], __float_as_int(w[i]));
    }
}

// ---------------- weight transpose + bf16: Wt[n][k] = bf16(W[k][n]) ----------------
// pad rows n in [N, Npad) with zeros so B-tile gload_lds never reads garbage

__global__ void transpose_w(const float* __restrict__ W, unsigned short* __restrict__ Wt,
                            int K, int N, int Npad) {
    int i = blockIdx.x * blockDim.x + threadIdx.x;
    if (i >= Npad * K) return;
    int n = i / K, k = i - n * K;
    float v = (n < N) ? W[(size_t)k * N + n] : 0.f;
    Wt[i] = f2bf(v);
}

// ---------------- bf16 MFMA GEMM (m97 structure): C[M,N] = A[M,K] @ Bt[N,K]^T ----------------
// BM=128, BK=64, 256 threads (4 waves). BN=128: waves 2x2 (64x64 wave tile).
// BN=64: waves 4x1 (32x64). Linear LDS, global_load_lds width-16 staging.

template <int BN, bool AF32>
__global__ __launch_bounds__(256) void gemm_mfma(const void* __restrict__ Av,
                                                 const unsigned short* __restrict__ Bt,
                                                 unsigned short* __restrict__ C,
                                                 int M, int K, int N) {
    constexpr int BM = 128, BK = 64;
    __shared__ unsigned short As[BM * BK];
    __shared__ unsigned short Bs[BN * BK];
    const int tid = threadIdx.x;
    const int lane = tid & 63, wid = tid >> 6;
    const int m0 = blockIdx.x * BM, n0 = blockIdx.y * BN;

    constexpr int WN = (BN == 128) ? 2 : 1;     // waves along N
    constexpr int WTM = (BN == 128) ? 64 : 32;  // wave tile M
    constexpr int FM = WTM / 16, FN = 4;        // 16x16 frags per wave
    const int wm = (wid / WN) * WTM;
    const int wn = (wid % WN) * 64;
    const int g = lane >> 4, r16 = lane & 15;

    const unsigned short* A16 = (const unsigned short*)Av;
    const float* A32 = (const float*)Av;

    f32x4 acc[FM][FN] = {};

    for (int k0 = 0; k0 < K; k0 += BK) {
        // ---- stage A tile 128x64 ----
        if constexpr (AF32) {
#pragma unroll
            for (int it = 0; it < 4; ++it) {
                int c = it * 256 + tid;          // 1024 chunks of 8
                int r = c >> 3, kc = c & 7;
                int gm = m0 + r;
                bf16x8 val;
                if (gm < M) {
                    const float* p = A32 + (size_t)gm * K + k0 + kc * 8;
                    float4 v0 = *reinterpret_cast<const float4*>(p);
                    float4 v1 = *reinterpret_cast<const float4*>(p + 4);
                    val[0] = (short)f2bf(v0.x); val[1] = (short)f2bf(v0.y);
                    val[2] = (short)f2bf(v0.z); val[3] = (short)f2bf(v0.w);
                    val[4] = (short)f2bf(v1.x); val[5] = (short)f2bf(v1.y);
                    val[6] = (short)f2bf(v1.z); val[7] = (short)f2bf(v1.w);
                } else {
#pragma unroll
                    for (int j = 0; j < 8; ++j) val[j] = 0;
                }
                *reinterpret_cast<bf16x8*>(&As[r * BK + kc * 8]) = val;
            }
        } else {
            // async DMA: each call stages 8 rows (64 lanes x 16B). A buffer lives in
            // d_ws with live regions after it, so tail-block OOB reads are safe garbage
            // (guarded at the epilogue store).
#pragma unroll
            for (int c = 0; c < 4; ++c) {
                int base = wid * 32 + c * 8;
                int row = base + (lane >> 3), kc = lane & 7;
                const unsigned short* gp = A16 + (size_t)(m0 + row) * K + k0 + kc * 8;
                __builtin_amdgcn_global_load_lds(
                    (const __attribute__((address_space(1))) void*)gp,
                    (__attribute__((address_space(3))) void*)&As[base * BK], 16, 0, 0);
            }
        }
        // ---- stage B tile BNx64 from row-major Bt (padded to BN rows) ----
        {
            constexpr int BCALLS = (BN * BK) / (512 * 4);  // per-wave calls: 4 (BN=128) / 2 (BN=64)
#pragma unroll
            for (int c = 0; c < BCALLS; ++c) {
                int base = wid * (BN / 4) + c * 8;
                int row = base + (lane >> 3), kc = lane & 7;
                const unsigned short* gp = Bt + (size_t)(n0 + row) * K + k0 + kc * 8;
                __builtin_amdgcn_global_load_lds(
                    (const __attribute__((address_space(1))) void*)gp,
                    (__attribute__((address_space(3))) void*)&Bs[base * BK], 16, 0, 0);
            }
        }
        __syncthreads();
        // ---- compute: 2 k-substeps of 32 ----
#pragma unroll
        for (int ks = 0; ks < 2; ++ks) {
            bf16x8 af[FM], bfr[FN];
#pragma unroll
            for (int i = 0; i < FM; ++i)
                af[i] = *reinterpret_cast<const bf16x8*>(&As[(wm + i * 16 + r16) * BK + ks * 32 + g * 8]);
#pragma unroll
            for (int j = 0; j < FN; ++j)
                bfr[j] = *reinterpret_cast<const bf16x8*>(&Bs[(wn + j * 16 + r16) * BK + ks * 32 + g * 8]);
#pragma unroll
            for (int i = 0; i < FM; ++i)
#pragma unroll
                for (int j = 0; j < FN; ++j)
                    acc[i][j] = __builtin_amdgcn_mfma_f32_16x16x32_bf16(af[i], bfr[j], acc[i][j], 0, 0, 0);
        }
        __syncthreads();
    }
    // ---- epilogue: D frag layout col=lane&15, row=(lane>>4)*4+r ----
#pragma unroll
    for (int i = 0; i < FM; ++i) {
        int gmBase = m0 + wm + i * 16 + g * 4;
#pragma unroll
        for (int j = 0; j < FN; ++j) {
            int gn = n0 + wn + j * 16 + r16;
            if (gn < N) {
#pragma unroll
                for (int r = 0; r < 4; ++r) {
                    int gm = gmBase + r;
                    if (gm < M) C[(size_t)gm * N + gn] = f2bf(acc[i][j][r]);
                }
            }
        }
    }
}

// ---------------- CSR aggregation (bf16 supp -> bf16 h), fused bias+ReLU ----------------
// one wave per node; 4-edge unrolled gather pipeline

template <int FO>
__global__ __launch_bounds__(256) void agg_kernel(const unsigned short* __restrict__ supp,
                                                  const int2* __restrict__ ep,
                                                  const int* __restrict__ rowptr,
                                                  const float* __restrict__ bias,
                                                  unsigned short* __restrict__ out, int n_nodes) {
    int node = (int)((blockIdx.x * blockDim.x + threadIdx.x) >> 6);
    int lane = threadIdx.x & 63;
    if (node >= n_nodes) return;
    int beg = rowptr[node], end = rowptr[node + 1];
    if constexpr (FO == 256) {
        float a0 = 0.f, a1 = 0.f, a2 = 0.f, a3 = 0.f;
        int e = beg;
        for (; e + 4 <= end; e += 4) {
            int2 e0 = ep[e], e1 = ep[e + 1], e2 = ep[e + 2], e3 = ep[e + 3];
            ushort4 v0 = *reinterpret_cast<const ushort4*>(supp + (size_t)e0.x * 256 + lane * 4);
            ushort4 v1 = *reinterpret_cast<const ushort4*>(supp + (size_t)e1.x * 256 + lane * 4);
            ushort4 v2 = *reinterpret_cast<const ushort4*>(supp + (size_t)e2.x * 256 + lane * 4);
            ushort4 v3 = *reinterpret_cast<const ushort4*>(supp + (size_t)e3.x * 256 + lane * 4);
            float w0 = __int_as_float(e0.y), w1 = __int_as_float(e1.y);
            float w2 = __int_as_float(e2.y), w3 = __int_as_float(e3.y);
            a0 += w0 * bf2f(v0.x) + w1 * bf2f(v1.x) + w2 * bf2f(v2.x) + w3 * bf2f(v3.x);
            a1 += w0 * bf2f(v0.y) + w1 * bf2f(v1.y) + w2 * bf2f(v2.y) + w3 * bf2f(v3.y);
            a2 += w0 * bf2f(v0.z) + w1 * bf2f(v1.z) + w2 * bf2f(v2.z) + w3 * bf2f(v3.z);
            a3 += w0 * bf2f(v0.w) + w1 * bf2f(v1.w) + w2 * bf2f(v2.w) + w3 * bf2f(v3.w);
        }
        for (; e < end; ++e) {
            int2 e0 = ep[e];
            float w = __int_as_float(e0.y);
            ushort4 v = *reinterpret_cast<const ushort4*>(supp + (size_t)e0.x * 256 + lane * 4);
            a0 += w * bf2f(v.x); a1 += w * bf2f(v.y);
            a2 += w * bf2f(v.z); a3 += w * bf2f(v.w);
        }
        float4 b = *reinterpret_cast<const float4*>(bias + lane * 4);
        a0 = fmaxf(a0 + b.x, 0.f); a1 = fmaxf(a1 + b.y, 0.f);
        a2 = fmaxf(a2 + b.z, 0.f); a3 = fmaxf(a3 + b.w, 0.f);
        ushort4 o = { f2bf(a0), f2bf(a1), f2bf(a2), f2bf(a3) };
        *reinterpret_cast<ushort4*>(out + (size_t)node * 256 + lane * 4) = o;
    } else if constexpr (FO == 128) {
        float a0 = 0.f, a1 = 0.f;
        int e = beg;
        for (; e + 4 <= end; e += 4) {
            int2 e0 = ep[e], e1 = ep[e + 1], e2 = ep[e + 2], e3 = ep[e + 3];
            ushort2 v0 = *reinterpret_cast<const ushort2*>(supp + (size_t)e0.x * 128 + lane * 2);
            ushort2 v1 = *reinterpret_cast<const ushort2*>(supp + (size_t)e1.x * 128 + lane * 2);
            ushort2 v2 = *reinterpret_cast<const ushort2*>(supp + (size_t)e2.x * 128 + lane * 2);
            ushort2 v3 = *reinterpret_cast<const ushort2*>(supp + (size_t)e3.x * 128 + lane * 2);
            float w0 = __int_as_float(e0.y), w1 = __int_as_float(e1.y);
            float w2 = __int_as_float(e2.y), w3 = __int_as_float(e3.y);
            a0 += w0 * bf2f(v0.x) + w1 * bf2f(v1.x) + w2 * bf2f(v2.x) + w3 * bf2f(v3.x);
            a1 += w0 * bf2f(v0.y) + w1 * bf2f(v1.y) + w2 * bf2f(v2.y) + w3 * bf2f(v3.y);
        }
        for (; e < end; ++e) {
            int2 e0 = ep[e];
            float w = __int_as_float(e0.y);
            ushort2 v = *reinterpret_cast<const ushort2*>(supp + (size_t)e0.x * 128 + lane * 2);
            a0 += w * bf2f(v.x); a1 += w * bf2f(v.y);
        }
        float2 b = *reinterpret_cast<const float2*>(bias + lane * 2);
        a0 = fmaxf(a0 + b.x, 0.f); a1 = fmaxf(a1 + b.y, 0.f);
        ushort2 o = { f2bf(a0), f2bf(a1) };
        *reinterpret_cast<ushort2*>(out + (size_t)node * 128 + lane * 2) = o;
    } else {  // FO == 64
        float a0 = 0.f;
        int e = beg;
        for (; e + 4 <= end; e += 4) {
            int2 e0 = ep[e], e1 = ep[e + 1], e2 = ep[e + 2], e3 = ep[e + 3];
            float v0 = bf2f(supp[(size_t)e0.x * 64 + lane]);
            float v1 = bf2f(supp[(size_t)e1.x * 64 + lane]);
            float v2 = bf2f(supp[(size_t)e2.x * 64 + lane]);
            float v3 = bf2f(supp[(size_t)e3.x * 64 + lane]);
            a0 += __int_as_float(e0.y) * v0 + __int_as_float(e1.y) * v1 +
                  __int_as_float(e2.y) * v2 + __int_as_float(e3.y) * v3;
        }
        for (; e < end; ++e) {
            int2 e0 = ep[e];
            a0 += __int_as_float(e0.y) * bf2f(supp[(size_t)e0.x * 64 + lane]);
        }
        a0 = fmaxf(a0 + bias[lane], 0.f);
        out[(size_t)node * 64 + lane] = f2bf(a0);
    }
}

// ---------------- final layer: aggregation + bias + log_softmax over 40 (f32 out) ----------------

__global__ __launch_bounds__(256) void agg_lsm_kernel(const unsigned short* __restrict__ supp,
                                                      const int2* __restrict__ ep,
                                                      const int* __restrict__ rowptr,
                                                      const float* __restrict__ bias,
                                                      float* __restrict__ out, int n_nodes) {
    int node = (int)((blockIdx.x * blockDim.x + threadIdx.x) >> 6);
    int lane = threadIdx.x & 63;
    if (node >= n_nodes) return;
    int beg = rowptr[node], end = rowptr[node + 1];
    float acc = 0.f;
    for (int e = beg; e < end; ++e) {
        int2 e0 = ep[e];
        float w = __int_as_float(e0.y);
        if (lane < 40) acc += w * bf2f(supp[(size_t)e0.x * 40 + lane]);
    }
    float v = (lane < 40) ? (acc + bias[lane]) : -1e30f;
    float m = v;
    for (int off = 32; off; off >>= 1) m = fmaxf(m, __shfl_xor(m, off));
    float ex = (lane < 40) ? expf(v - m) : 0.f;
    float s = ex;
    for (int off = 32; off; off >>= 1) s += __shfl_xor(s, off);
    float ls = logf(s);
    if (lane < 40) out[(size_t)node * 40 + lane] = v - m - ls;
}

// ---------------- launch ----------------

extern "C" void kernel_launch(void* const* d_in, const int* in_sizes, int n_in,
                              void* d_out, int out_size, void* d_ws, size_t ws_size,
                              hipStream_t stream) {
    const float* x    = (const float*)d_in[0];
    const int*   esrc = (const int*)d_in[1];
    const int*   edst = (const int*)d_in[2];
    const float* ew   = (const float*)d_in[3];
    const float* W[9];
    const float* b[9];
    for (int i = 0; i < 9; ++i) {
        W[i] = (const float*)d_in[4 + 2 * i];
        b[i] = (const float*)d_in[5 + 2 * i];
    }
    const int nN = in_sizes[0] / 512;  // 100000
    const int nE = in_sizes[1];        // 3200000

    const int dims[10] = {512, 256, 256, 256, 256, 256, 128, 128, 64, 40};

    // ---- workspace layout (order matters: GEMM A-tile tail blocks read up to
    // ~48KB past h/supp; keep live regions after them) ----
    char* ws = (char*)d_ws;
    unsigned short* h    = (unsigned short*)ws;                       // nN*256 bf16
    unsigned short* supp = (unsigned short*)(ws + (size_t)nN * 256 * 2);
    char* p = ws + (size_t)nN * 256 * 2 * 2;
    unsigned short* Wt = (unsigned short*)p; p += (1 << 21);          // 2 MB padded bf16 W^T
    int* deg    = (int*)p; p += ((size_t)nN + 64) * 4;
    int* rowptr = (int*)p; p += ((size_t)nN + 64) * 4;
    int* cursor = (int*)p; p += ((size_t)nN + 64) * 4;
    int2* ep    = (int2*)p; p += (size_t)nE * 8;

    // ---- transpose+convert weights: Wt[i] is [fo_pad][fi] row-major ----
    size_t woff[9];
    {
        size_t off = 0;
        for (int i = 0; i < 9; ++i) {
            woff[i] = off;
            int fi = dims[i], fo = dims[i + 1];
            int fop = cdiv(fo, 64) * 64;
            int sz = fop * fi;
            transpose_w<<<cdiv(sz, 256), 256, 0, stream>>>(W[i], Wt + off, fi, fo, fop);
            off += (size_t)sz;
        }
    }

    // ---- build CSR ----
    hipMemsetAsync(deg, 0, (size_t)nN * 4, stream);
    count_deg_kernel<<<cdiv(nE, 256), 256, 0, stream>>>(edst, deg, nE);
    scan_kernel<<<1, 256, 0, stream>>>(deg, rowptr, cursor, nN);
    scatter_kernel<<<cdiv(nE, 256), 256, 0, stream>>>(esrc, edst, ew, cursor, ep, nE);

    const int aggBlocks = cdiv(nN, 4);  // 4 waves/block, 1 node/wave

    const void* A = (const void*)x;
    for (int L = 0; L < 9; ++L) {
        int fi = dims[L], fo = dims[L + 1];
        int BN = (fo >= 128) ? 128 : 64;
        dim3 g(cdiv(nN, 128), cdiv(fo, BN));
        if (L == 0) {
            gemm_mfma<128, true><<<g, 256, 0, stream>>>(A, Wt + woff[L], supp, nN, fi, fo);
        } else if (BN == 128) {
            gemm_mfma<128, false><<<g, 256, 0, stream>>>(A, Wt + woff[L], supp, nN, fi, fo);
        } else {
            gemm_mfma<64, false><<<g, 256, 0, stream>>>(A, Wt + woff[L], supp, nN, fi, fo);
        }
        if (L < 8) {
            if (fo == 256)
                agg_kernel<256><<<aggBlocks, 256, 0, stream>>>(supp, ep, rowptr, b[L], h, nN);
            else if (fo == 128)
                agg_kernel<128><<<aggBlocks, 256, 0, stream>>>(supp, ep, rowptr, b[L], h, nN);
            else
                agg_kernel<64><<<aggBlocks, 256, 0, stream>>>(supp, ep, rowptr, b[L], h, nN);
            A = (const void*)h;
        } else {
            agg_lsm_kernel<<<aggBlocks, 256, 0, stream>>>(supp, ep, rowptr, b[8], (float*)d_out, nN);
        }
    }
}

// Round 4
// 2314.782 us; speedup vs baseline: 3.3487x; 1.0804x over previous
//
#include <hip/hip_runtime.h>
#include <cstdint>
#include <cstddef>

typedef __attribute__((ext_vector_type(8))) short bf16x8;   // 8 bf16 in 4 VGPRs
typedef __attribute__((ext_vector_type(4))) float f32x4;    // MFMA accumulator

static inline int cdiv(int a, int b) { return (a + b - 1) / b; }

__device__ inline unsigned short f2bf(float f) {
    union { float f; unsigned int u; } v; v.f = f;
    unsigned int u = v.u;
    return (unsigned short)((u + 0x7FFFu + ((u >> 16) & 1u)) >> 16);  // RNE
}
__device__ inline float bf2f(unsigned short b) {
    union { unsigned int u; float f; } v; v.u = ((unsigned int)b) << 16;
    return v.f;
}

// ---------------- CSR build (counting sort by dst) ----------------

__global__ void count_deg_kernel(const int* __restrict__ dst, int* __restrict__ deg, int nE) {
    int i = blockIdx.x * blockDim.x + threadIdx.x;
    if (i < nE) atomicAdd(&deg[dst[i]], 1);
}

__global__ void scan_kernel(const int* __restrict__ deg, int* __restrict__ rowptr,
                            int* __restrict__ cursor, int n) {
    __shared__ int sdata[256];
    __shared__ int carry_s;
    int tid = threadIdx.x;
    if (tid == 0) carry_s = 0;
    __syncthreads();
    for (int base = 0; base < n; base += 1024) {
        int vals[4];
        int local = 0;
#pragma unroll
        for (int i = 0; i < 4; ++i) {
            int idx = base + tid * 4 + i;
            vals[i] = (idx < n) ? deg[idx] : 0;
            local += vals[i];
        }
        sdata[tid] = local;
        __syncthreads();
        for (int off = 1; off < 256; off <<= 1) {
            int t = (tid >= off) ? sdata[tid - off] : 0;
            __syncthreads();
            sdata[tid] += t;
            __syncthreads();
        }
        int excl = sdata[tid] - local;
        int c0 = carry_s;
        int run = c0 + excl;
#pragma unroll
        for (int i = 0; i < 4; ++i) {
            int idx = base + tid * 4 + i;
            if (idx < n) { rowptr[idx] = run; cursor[idx] = run; }
            run += vals[i];
        }
        __syncthreads();
        if (tid == 255) carry_s = c0 + sdata[255];
        __syncthreads();
    }
    if (tid == 0) rowptr[n] = carry_s;
}

__global__ void scatter_kernel(const int* __restrict__ src, const int* __restrict__ dst,
                               const float* __restrict__ w, int* __restrict__ cursor,
                               int2* __restrict__ ep, int nE) {
    int i = blockIdx.x * blockDim.x + threadIdx.x;
    if (i < nE) {
        int d = dst[i];
        int pos = atomicAdd(&cursor[d], 1);
        ep[pos] = make_int2(src[i], __float_as_int(w[i]));
    }
}

// ---------------- weight transpose + bf16: Wt[n][k] = bf16(W[k][n]) ----------------

__global__ void transpose_w(const float* __restrict__ W, unsigned short* __restrict__ Wt,
                            int K, int N, int Npad) {
    int i = blockIdx.x * blockDim.x + threadIdx.x;
    if (i >= Npad * K) return;
    int n = i / K, k = i - n * K;
    float v = (n < N) ? W[(size_t)k * N + n] : 0.f;
    Wt[i] = f2bf(v);
}

// ---------------- bf16 MFMA GEMM (m97 structure): C[M,N] = A[M,K] @ Bt[N,K]^T ----------------

template <int BN, bool AF32>
__global__ __launch_bounds__(256) void gemm_mfma(const void* __restrict__ Av,
                                                 const unsigned short* __restrict__ Bt,
                                                 unsigned short* __restrict__ C,
                                                 int M, int K, int N) {
    constexpr int BM = 128, BK = 64;
    __shared__ unsigned short As[BM * BK];
    __shared__ unsigned short Bs[BN * BK];
    const int tid = threadIdx.x;
    const int lane = tid & 63, wid = tid >> 6;
    const int m0 = blockIdx.x * BM, n0 = blockIdx.y * BN;

    constexpr int WN = (BN == 128) ? 2 : 1;
    constexpr int WTM = (BN == 128) ? 64 : 32;
    constexpr int FM = WTM / 16, FN = 4;
    const int wm = (wid / WN) * WTM;
    const int wn = (wid % WN) * 64;
    const int g = lane >> 4, r16 = lane & 15;

    const unsigned short* A16 = (const unsigned short*)Av;
    const float* A32 = (const float*)Av;

    f32x4 acc[FM][FN] = {};

    for (int k0 = 0; k0 < K; k0 += BK) {
        if constexpr (AF32) {
#pragma unroll
            for (int it = 0; it < 4; ++it) {
                int c = it * 256 + tid;
                int r = c >> 3, kc = c & 7;
                int gm = m0 + r;
                bf16x8 val;
                if (gm < M) {
                    const float* p = A32 + (size_t)gm * K + k0 + kc * 8;
                    float4 v0 = *reinterpret_cast<const float4*>(p);
                    float4 v1 = *reinterpret_cast<const float4*>(p + 4);
                    val[0] = (short)f2bf(v0.x); val[1] = (short)f2bf(v0.y);
                    val[2] = (short)f2bf(v0.z); val[3] = (short)f2bf(v0.w);
                    val[4] = (short)f2bf(v1.x); val[5] = (short)f2bf(v1.y);
                    val[6] = (short)f2bf(v1.z); val[7] = (short)f2bf(v1.w);
                } else {
#pragma unroll
                    for (int j = 0; j < 8; ++j) val[j] = 0;
                }
                *reinterpret_cast<bf16x8*>(&As[r * BK + kc * 8]) = val;
            }
        } else {
#pragma unroll
            for (int c = 0; c < 4; ++c) {
                int base = wid * 32 + c * 8;
                int row = base + (lane >> 3), kc = lane & 7;
                const unsigned short* gp = A16 + (size_t)(m0 + row) * K + k0 + kc * 8;
                __builtin_amdgcn_global_load_lds(
                    (const __attribute__((address_space(1))) void*)gp,
                    (__attribute__((address_space(3))) void*)&As[base * BK], 16, 0, 0);
            }
        }
        {
            constexpr int BCALLS = (BN * BK) / (512 * 4);
#pragma unroll
            for (int c = 0; c < BCALLS; ++c) {
                int base = wid * (BN / 4) + c * 8;
                int row = base + (lane >> 3), kc = lane & 7;
                const unsigned short* gp = Bt + (size_t)(n0 + row) * K + k0 + kc * 8;
                __builtin_amdgcn_global_load_lds(
                    (const __attribute__((address_space(1))) void*)gp,
                    (__attribute__((address_space(3))) void*)&Bs[base * BK], 16, 0, 0);
            }
        }
        __syncthreads();
#pragma unroll
        for (int ks = 0; ks < 2; ++ks) {
            bf16x8 af[FM], bfr[FN];
#pragma unroll
            for (int i = 0; i < FM; ++i)
                af[i] = *reinterpret_cast<const bf16x8*>(&As[(wm + i * 16 + r16) * BK + ks * 32 + g * 8]);
#pragma unroll
            for (int j = 0; j < FN; ++j)
                bfr[j] = *reinterpret_cast<const bf16x8*>(&Bs[(wn + j * 16 + r16) * BK + ks * 32 + g * 8]);
#pragma unroll
            for (int i = 0; i < FM; ++i)
#pragma unroll
                for (int j = 0; j < FN; ++j)
                    acc[i][j] = __builtin_amdgcn_mfma_f32_16x16x32_bf16(af[i], bfr[j], acc[i][j], 0, 0, 0);
        }
        __syncthreads();
    }
#pragma unroll
    for (int i = 0; i < FM; ++i) {
        int gmBase = m0 + wm + i * 16 + g * 4;
#pragma unroll
        for (int j = 0; j < FN; ++j) {
            int gn = n0 + wn + j * 16 + r16;
            if (gn < N) {
#pragma unroll
                for (int r = 0; r < 4; ++r) {
                    int gm = gmBase + r;
                    if (gm < M) C[(size_t)gm * N + gn] = f2bf(acc[i][j][r]);
                }
            }
        }
    }
}

// ---------------- CSR aggregation (bf16 supp -> bf16 h), fused bias+ReLU ----------------
// one wave per node; 8-edge unrolled gather pipeline

template <int FO>
__global__ __launch_bounds__(256) void agg_kernel(const unsigned short* __restrict__ supp,
                                                  const int2* __restrict__ ep,
                                                  const int* __restrict__ rowptr,
                                                  const float* __restrict__ bias,
                                                  unsigned short* __restrict__ out, int n_nodes) {
    int node = (int)((blockIdx.x * blockDim.x + threadIdx.x) >> 6);
    int lane = threadIdx.x & 63;
    if (node >= n_nodes) return;
    int beg = rowptr[node], end = rowptr[node + 1];
    if constexpr (FO == 256) {
        float a0 = 0.f, a1 = 0.f, a2 = 0.f, a3 = 0.f;
        int e = beg;
        for (; e + 8 <= end; e += 8) {
            int2 ee[8];
#pragma unroll
            for (int u = 0; u < 8; ++u) ee[u] = ep[e + u];
            ushort4 vv[8];
#pragma unroll
            for (int u = 0; u < 8; ++u)
                vv[u] = *reinterpret_cast<const ushort4*>(supp + (size_t)ee[u].x * 256 + lane * 4);
#pragma unroll
            for (int u = 0; u < 8; ++u) {
                float w = __int_as_float(ee[u].y);
                a0 += w * bf2f(vv[u].x); a1 += w * bf2f(vv[u].y);
                a2 += w * bf2f(vv[u].z); a3 += w * bf2f(vv[u].w);
            }
        }
        for (; e < end; ++e) {
            int2 e0 = ep[e];
            float w = __int_as_float(e0.y);
            ushort4 v = *reinterpret_cast<const ushort4*>(supp + (size_t)e0.x * 256 + lane * 4);
            a0 += w * bf2f(v.x); a1 += w * bf2f(v.y);
            a2 += w * bf2f(v.z); a3 += w * bf2f(v.w);
        }
        float4 b = *reinterpret_cast<const float4*>(bias + lane * 4);
        a0 = fmaxf(a0 + b.x, 0.f); a1 = fmaxf(a1 + b.y, 0.f);
        a2 = fmaxf(a2 + b.z, 0.f); a3 = fmaxf(a3 + b.w, 0.f);
        ushort4 o = { f2bf(a0), f2bf(a1), f2bf(a2), f2bf(a3) };
        *reinterpret_cast<ushort4*>(out + (size_t)node * 256 + lane * 4) = o;
    } else if constexpr (FO == 128) {
        float a0 = 0.f, a1 = 0.f;
        int e = beg;
        for (; e + 8 <= end; e += 8) {
            int2 ee[8];
#pragma unroll
            for (int u = 0; u < 8; ++u) ee[u] = ep[e + u];
            ushort2 vv[8];
#pragma unroll
            for (int u = 0; u < 8; ++u)
                vv[u] = *reinterpret_cast<const ushort2*>(supp + (size_t)ee[u].x * 128 + lane * 2);
#pragma unroll
            for (int u = 0; u < 8; ++u) {
                float w = __int_as_float(ee[u].y);
                a0 += w * bf2f(vv[u].x); a1 += w * bf2f(vv[u].y);
            }
        }
        for (; e < end; ++e) {
            int2 e0 = ep[e];
            float w = __int_as_float(e0.y);
            ushort2 v = *reinterpret_cast<const ushort2*>(supp + (size_t)e0.x * 128 + lane * 2);
            a0 += w * bf2f(v.x); a1 += w * bf2f(v.y);
        }
        float2 b = *reinterpret_cast<const float2*>(bias + lane * 2);
        a0 = fmaxf(a0 + b.x, 0.f); a1 = fmaxf(a1 + b.y, 0.f);
        ushort2 o = { f2bf(a0), f2bf(a1) };
        *reinterpret_cast<ushort2*>(out + (size_t)node * 128 + lane * 2) = o;
    } else {  // FO == 64
        float a0 = 0.f;
        int e = beg;
        for (; e + 8 <= end; e += 8) {
            int2 ee[8];
#pragma unroll
            for (int u = 0; u < 8; ++u) ee[u] = ep[e + u];
            float vv[8];
#pragma unroll
            for (int u = 0; u < 8; ++u)
                vv[u] = bf2f(supp[(size_t)ee[u].x * 64 + lane]);
#pragma unroll
            for (int u = 0; u < 8; ++u)
                a0 += __int_as_float(ee[u].y) * vv[u];
        }
        for (; e < end; ++e) {
            int2 e0 = ep[e];
            a0 += __int_as_float(e0.y) * bf2f(supp[(size_t)e0.x * 64 + lane]);
        }
        a0 = fmaxf(a0 + bias[lane], 0.f);
        out[(size_t)node * 64 + lane] = f2bf(a0);
    }
}

// ---------------- final layer: padded-64 supp, agg + bias + log_softmax (f32 out) ----------------
// supp stride 64; cols 40..63 are exact zeros (zero-padded Wt rows)

__global__ __launch_bounds__(256) void agg_lsm_kernel(const unsigned short* __restrict__ supp,
                                                      const int2* __restrict__ ep,
                                                      const int* __restrict__ rowptr,
                                                      const float* __restrict__ bias,
                                                      float* __restrict__ out, int n_nodes) {
    int node = (int)((blockIdx.x * blockDim.x + threadIdx.x) >> 6);
    int lane = threadIdx.x & 63;
    if (node >= n_nodes) return;
    int beg = rowptr[node], end = rowptr[node + 1];
    float acc = 0.f;
    int e = beg;
    for (; e + 8 <= end; e += 8) {
        int2 ee[8];
#pragma unroll
        for (int u = 0; u < 8; ++u) ee[u] = ep[e + u];
        float vv[8];
#pragma unroll
        for (int u = 0; u < 8; ++u)
            vv[u] = bf2f(supp[(size_t)ee[u].x * 64 + lane]);
#pragma unroll
        for (int u = 0; u < 8; ++u)
            acc += __int_as_float(ee[u].y) * vv[u];
    }
    for (; e < end; ++e) {
        int2 e0 = ep[e];
        acc += __int_as_float(e0.y) * bf2f(supp[(size_t)e0.x * 64 + lane]);
    }
    float bv = (lane < 40) ? bias[lane] : 0.f;
    float v = (lane < 40) ? (acc + bv) : -1e30f;
    float m = v;
    for (int off = 32; off; off >>= 1) m = fmaxf(m, __shfl_xor(m, off));
    float ex = (lane < 40) ? expf(v - m) : 0.f;
    float s = ex;
    for (int off = 32; off; off >>= 1) s += __shfl_xor(s, off);
    float ls = logf(s);
    if (lane < 40) out[(size_t)node * 40 + lane] = v - m - ls;
}

// ---------------- launch ----------------

extern "C" void kernel_launch(void* const* d_in, const int* in_sizes, int n_in,
                              void* d_out, int out_size, void* d_ws, size_t ws_size,
                              hipStream_t stream) {
    const float* x    = (const float*)d_in[0];
    const int*   esrc = (const int*)d_in[1];
    const int*   edst = (const int*)d_in[2];
    const float* ew   = (const float*)d_in[3];
    const float* W[9];
    const float* b[9];
    for (int i = 0; i < 9; ++i) {
        W[i] = (const float*)d_in[4 + 2 * i];
        b[i] = (const float*)d_in[5 + 2 * i];
    }
    const int nN = in_sizes[0] / 512;  // 100000
    const int nE = in_sizes[1];        // 3200000

    const int dims[10] = {512, 256, 256, 256, 256, 256, 128, 128, 64, 40};

    // ---- workspace layout (GEMM A-tile tail blocks read up to ~48KB past h/supp;
    // keep live regions after them) ----
    char* ws = (char*)d_ws;
    unsigned short* h    = (unsigned short*)ws;                       // nN*256 bf16
    unsigned short* supp = (unsigned short*)(ws + (size_t)nN * 256 * 2);
    char* p = ws + (size_t)nN * 256 * 2 * 2;
    unsigned short* Wt = (unsigned short*)p; p += (1 << 21);          // padded bf16 W^T
    int* deg    = (int*)p; p += ((size_t)nN + 64) * 4;
    int* rowptr = (int*)p; p += ((size_t)nN + 64) * 4;
    int* cursor = (int*)p; p += ((size_t)nN + 64) * 4;
    int2* ep    = (int2*)p; p += (size_t)nE * 8;

    // ---- transpose+convert weights: Wt[i] is [fo_pad][fi] row-major ----
    size_t woff[9];
    {
        size_t off = 0;
        for (int i = 0; i < 9; ++i) {
            woff[i] = off;
            int fi = dims[i], fo = dims[i + 1];
            int fop = cdiv(fo, 64) * 64;
            int sz = fop * fi;
            transpose_w<<<cdiv(sz, 256), 256, 0, stream>>>(W[i], Wt + off, fi, fo, fop);
            off += (size_t)sz;
        }
    }

    // ---- build CSR ----
    hipMemsetAsync(deg, 0, (size_t)nN * 4, stream);
    count_deg_kernel<<<cdiv(nE, 256), 256, 0, stream>>>(edst, deg, nE);
    scan_kernel<<<1, 256, 0, stream>>>(deg, rowptr, cursor, nN);
    scatter_kernel<<<cdiv(nE, 256), 256, 0, stream>>>(esrc, edst, ew, cursor, ep, nE);

    const int aggBlocks = cdiv(nN, 4);  // 4 waves/block, 1 node/wave

    const void* A = (const void*)x;
    for (int L = 0; L < 9; ++L) {
        int fi = dims[L], fo = dims[L + 1];
        if (L == 8) {
            // padded final layer: compute 64 cols (40..63 are zeros), stride 64
            dim3 g(cdiv(nN, 128), 1);
            gemm_mfma<64, false><<<g, 256, 0, stream>>>(A, Wt + woff[L], supp, nN, fi, 64);
            agg_lsm_kernel<<<aggBlocks, 256, 0, stream>>>(supp, ep, rowptr, b[8], (float*)d_out, nN);
            break;
        }
        int BN = (fo >= 128) ? 128 : 64;
        dim3 g(cdiv(nN, 128), cdiv(fo, BN));
        if (L == 0) {
            gemm_mfma<128, true><<<g, 256, 0, stream>>>(A, Wt + woff[L], supp, nN, fi, fo);
        } else if (BN == 128) {
            gemm_mfma<128, false><<<g, 256, 0, stream>>>(A, Wt + woff[L], supp, nN, fi, fo);
        } else {
            gemm_mfma<64, false><<<g, 256, 0, stream>>>(A, Wt + woff[L], supp, nN, fi, fo);
        }
        if (fo == 256)
            agg_kernel<256><<<aggBlocks, 256, 0, stream>>>(supp, ep, rowptr, b[L], h, nN);
        else if (fo == 128)
            agg_kernel<128><<<aggBlocks, 256, 0, stream>>>(supp, ep, rowptr, b[L], h, nN);
        else
            agg_kernel<64><<<aggBlocks, 256, 0, stream>>>(supp, ep, rowptr, b[L], h, nN);
        A = (const void*)h;
    }
}